// Round 10
// baseline (95.383 us; speedup 1.0000x reference)
//
#include <hip/hip_runtime.h>

#define KDIM 1024
#define NDIM 16384
#define CHUNKS 256
#define CLEN 64   // NDIM / CHUNKS
#define KTILES 16 // KDIM / 64

typedef __bf16 bf16_t;
typedef bf16_t bf16x8 __attribute__((ext_vector_type(8)));
typedef bf16_t bf16x4 __attribute__((ext_vector_type(4)));
typedef float f32x4 __attribute__((ext_vector_type(4)));

__device__ __forceinline__ void gload_lds16(const bf16_t* g, bf16_t* l) {
  __builtin_amdgcn_global_load_lds(
      (const __attribute__((address_space(1))) void*)g,
      (__attribute__((address_space(3))) void*)l, 16, 0, 0);
}

// ---------------- fused: scan phase1 (coalesced, one row/block) + prefix + obs->u8 + hmu
//                  blocks >= 1024: halpha fp32->bf16 convert ----------------
__global__ __launch_bounds__(256) void k_phase1(const float* __restrict__ obs,
                                                const float* __restrict__ hbeta,
                                                float* __restrict__ carry,
                                                float* __restrict__ hmu,
                                                const float* __restrict__ A,
                                                bf16_t* __restrict__ Ab,
                                                unsigned char* __restrict__ obs8) {
  if (blockIdx.x >= 1024) {
    size_t i = ((size_t)(blockIdx.x - 1024) * 256 + threadIdx.x) * 4;
    float4 v = *reinterpret_cast<const float4*>(A + i);
    bf16x4 o;
    o[0] = (bf16_t)v.x; o[1] = (bf16_t)v.y; o[2] = (bf16_t)v.z; o[3] = (bf16_t)v.w;
    *reinterpret_cast<bf16x4*>(Ab + i) = o;
    return;
  }
  __shared__ unsigned char s8[256][68];   // bank (17c + t/4)%32: 2-way max (free)
  __shared__ float sm[256], sa[256];
  __shared__ float wred[4];
  int tid = threadIdx.x;
  int k = blockIdx.x;                     // one obs row per block
  float beta = hbeta[0];
  float decay = expf(-beta);
  const float* p = obs + (size_t)k * NDIM;
  unsigned char* po = obs8 + (size_t)k * NDIM;
  float sum = 0.f;
#pragma unroll
  for (int w = 0; w < 16; ++w) {
    float4 v = *reinterpret_cast<const float4*>(p + w * 1024 + tid * 4);
    sum += v.x + v.y + v.z + v.w;
    uchar4 u;
    u.x = (unsigned char)v.x; u.y = (unsigned char)v.y;
    u.z = (unsigned char)v.z; u.w = (unsigned char)v.w;
    *reinterpret_cast<uchar4*>(po + w * 1024 + tid * 4) = u;          // coalesced
    int c = w * 16 + (tid >> 4), t = 4 * (tid & 15);
    *reinterpret_cast<uchar4*>(&s8[c][t]) = u;
  }
  __syncthreads();
  float S = 0.f;
#pragma unroll 8
  for (int t = 0; t < CLEN; ++t)
    S = decay * (S + beta * (float)s8[tid][t]);
  float dL = expf(-beta * (float)CLEN);
  sm[tid] = dL; sa[tid] = S;
  __syncthreads();
#pragma unroll
  for (int s = 1; s < 256; s <<= 1) {
    float mp = 0.f, ap = 0.f;
    bool act = (tid >= s);
    if (act) { mp = sm[tid - s]; ap = sa[tid - s]; }
    __syncthreads();
    if (act) { sa[tid] += sm[tid] * ap; sm[tid] *= mp; }
    __syncthreads();
  }
  carry[(size_t)k * CHUNKS + tid] = (tid == 0) ? 0.f : sa[tid - 1];   // exclusive
  sum += __shfl_down(sum, 32); sum += __shfl_down(sum, 16);
  sum += __shfl_down(sum, 8);  sum += __shfl_down(sum, 4);
  sum += __shfl_down(sum, 2);  sum += __shfl_down(sum, 1);
  if ((tid & 63) == 0) wred[tid >> 6] = sum;
  __syncthreads();
  if (tid == 0)
    hmu[k] = (wred[0] + wred[1] + wred[2] + wred[3]) * (1.0f / NDIM) * 0.1f + 0.01f;
}

// ---------------- scan phase 3: full scan with carry (obs8 input), write S_all [t][j] bf16 ----------------
__global__ __launch_bounds__(64) void k_phase3(const unsigned char* __restrict__ obs8,
                                               const float* __restrict__ hbeta,
                                               const float* __restrict__ carry,
                                               bf16_t* __restrict__ S_all) {
  int c  = blockIdx.x & (CHUNKS - 1);
  int kb = blockIdx.x >> 8;
  int lane = threadIdx.x;
  float beta = hbeta[0];
  float decay = expf(-beta);
  __shared__ unsigned char s8[64][68];
  __shared__ bf16_t out_s[64][72];
  int k0 = kb * 64, t0 = c * CLEN;
  const unsigned char* base = obs8 + (size_t)k0 * NDIM + t0;
#pragma unroll 4
  for (int w = 0; w < 16; ++w) {
    int r = w * 4 + (lane >> 4), col = (lane & 15) * 4;
    *reinterpret_cast<uchar4*>(&s8[r][col]) =
        *reinterpret_cast<const uchar4*>(base + (size_t)r * NDIM + col);
  }
  __syncthreads();
  float S = carry[(size_t)(k0 + lane) * CHUNKS + c];
#pragma unroll 8
  for (int t = 0; t < CLEN; ++t) {
    out_s[t][lane] = (bf16_t)S;
    S = decay * (S + beta * (float)s8[lane][t]);
  }
  __syncthreads();
#pragma unroll 4
  for (int t = 0; t < CLEN; ++t)
    S_all[(size_t)(t0 + t) * KDIM + k0 + lane] = out_s[t][lane];
}

// ---------------- GEMM lam1 = halpha @ S_all^T, fused softplus + loglik ----------------
// 256x256, BK=64, 8 waves (2Mx4N). TRUE 8-phase (4 phases/K-tile, 2 barriers each):
// per phase {ds_read subtile; staged rounds; barrier; lgkmcnt(0); setprio; 16 MFMA; barrier}.
// Staging ledger (64-row rounds): tile t issues ph0:[t+1.A1,A3] ph2:[t+2.A0,A2,B0,B1]
// ph3:[t+2.B2,B3]; single counted vmcnt(6) in ph3 gates tile t+1 (never drains).
// Same-buffer t+2 writes only touch regions dead since ph1 (early-A rows, B-in-regs)
// -> barrier-ordered, race-free. LDS XOR-swizzle via pre-swizzled global source.
__global__ __launch_bounds__(512, 2) void k_gemm(const bf16_t* __restrict__ Ab,
                                                 const bf16_t* __restrict__ Bb,
                                                 const float* __restrict__ hmu,
                                                 const unsigned char* __restrict__ obs8,
                                                 float* __restrict__ out) {
  __shared__ bf16_t As[2][256 * 64];
  __shared__ bf16_t Bs[2][256 * 64];
  int tid = threadIdx.x;
  int b = blockIdx.x;
  int lb = (b & 7) * 32 + (b >> 3);
  int kb = lb & 3;            // M-tile (4)
  int tb = lb >> 2;           // N-tile (64)
  int lane = tid & 63, wid = tid >> 6;
  int wm = wid >> 2, wn = wid & 3;          // 2x4 waves, each 128x64 output
  int r15 = lane & 15, h = lane >> 4;
  f32x4 acc[8][4] = {};

  // round i covers rows i*64..i*64+63; source pre-swizzled (sl = sp ^ (row&7))
  const bf16_t* gA[4];
  const bf16_t* gB[4];
#pragma unroll
  for (int i = 0; i < 4; ++i) {
    int slot = i * 512 + tid;
    int row = slot >> 3, sp = slot & 7;
    int sl = sp ^ (row & 7);
    gA[i] = Ab + (size_t)(kb * 256 + row) * KDIM + sl * 8;
    gB[i] = Bb + (size_t)(tb * 256 + row) * KDIM + sl * 8;
  }

#define SA(buf, kk, i) gload_lds16(gA[i] + (kk), &As[buf][((i) * 512 + wid * 64) * 8])
#define SB(buf, kk, i) gload_lds16(gB[i] + (kk), &Bs[buf][((i) * 512 + wid * 64) * 8])
#define AF(buf, mi, sl) (*reinterpret_cast<const bf16x8*>( \
    &As[buf][(wm * 128 + (mi) * 16 + r15) * 64 + ((((sl)) ^ ((wm * 128 + (mi) * 16 + r15) & 7)) * 8)]))
#define BF(buf, ni, sl) (*reinterpret_cast<const bf16x8*>( \
    &Bs[buf][(wn * 64 + (ni) * 16 + r15) * 64 + ((((sl)) ^ ((wn * 64 + (ni) * 16 + r15) & 7)) * 8)]))
#define LGKM0 do { asm volatile("s_waitcnt lgkmcnt(0)" ::: "memory"); \
                   __builtin_amdgcn_sched_barrier(0); } while (0)
#define SB0 __builtin_amdgcn_sched_barrier(0)

  // prologue: tile0 all 8 rounds, then tile1 early-6 (A0,A2,B0..B3)
  SA(0, 0, 0); SA(0, 0, 1); SA(0, 0, 2); SA(0, 0, 3);
  SB(0, 0, 0); SB(0, 0, 1); SB(0, 0, 2); SB(0, 0, 3);
  SB0;
  SA(1, 64, 0); SA(1, 64, 2);
  SB(1, 64, 0); SB(1, 64, 1); SB(1, 64, 2); SB(1, 64, 3);
  SB0;
  asm volatile("s_waitcnt vmcnt(6)" ::: "memory");   // tile0's 8 retired
  __builtin_amdgcn_s_barrier();

  for (int t = 0; t < KTILES; ++t) {
    const int cur = t & 1;
    const int kk1 = (t + 1) * 64, kk2 = (t + 2) * 64;
    bf16x8 a[4], bk0[4], bk1[4];
    // ---- ph0: A mi0-3 kh0 + B kh0 ----
#pragma unroll
    for (int m = 0; m < 4; ++m) a[m] = AF(cur, m, h);
#pragma unroll
    for (int n = 0; n < 4; ++n) bk0[n] = BF(cur, n, h);
    if (t + 1 < KTILES) { SA(cur ^ 1, kk1, 1); SA(cur ^ 1, kk1, 3); }  // t+1 late-A (other buf)
    SB0;
    __builtin_amdgcn_s_barrier();
    LGKM0;
    __builtin_amdgcn_s_setprio(1);
#pragma unroll
    for (int m = 0; m < 4; ++m)
#pragma unroll
      for (int n = 0; n < 4; ++n)
        acc[m][n] = __builtin_amdgcn_mfma_f32_16x16x32_bf16(a[m], bk0[n], acc[m][n], 0, 0, 0);
    __builtin_amdgcn_s_setprio(0);
    __builtin_amdgcn_s_barrier();
    // ---- ph1: A mi0-3 kh1 + B kh1 ----
#pragma unroll
    for (int m = 0; m < 4; ++m) a[m] = AF(cur, m, 4 + h);
#pragma unroll
    for (int n = 0; n < 4; ++n) bk1[n] = BF(cur, n, 4 + h);
    SB0;
    __builtin_amdgcn_s_barrier();
    LGKM0;
    __builtin_amdgcn_s_setprio(1);
#pragma unroll
    for (int m = 0; m < 4; ++m)
#pragma unroll
      for (int n = 0; n < 4; ++n)
        acc[m][n] = __builtin_amdgcn_mfma_f32_16x16x32_bf16(a[m], bk1[n], acc[m][n], 0, 0, 0);
    __builtin_amdgcn_s_setprio(0);
    __builtin_amdgcn_s_barrier();
    // ---- ph2: A mi4-7 kh0 (B reused from regs); stage t+2 early rounds ----
#pragma unroll
    for (int m = 0; m < 4; ++m) a[m] = AF(cur, 4 + m, h);
    if (t + 2 < KTILES) { SA(cur, kk2, 0); SA(cur, kk2, 2); SB(cur, kk2, 0); SB(cur, kk2, 1); }
    SB0;
    __builtin_amdgcn_s_barrier();
    LGKM0;
    __builtin_amdgcn_s_setprio(1);
#pragma unroll
    for (int m = 0; m < 4; ++m)
#pragma unroll
      for (int n = 0; n < 4; ++n)
        acc[4 + m][n] = __builtin_amdgcn_mfma_f32_16x16x32_bf16(a[m], bk0[n], acc[4 + m][n], 0, 0, 0);
    __builtin_amdgcn_s_setprio(0);
    __builtin_amdgcn_s_barrier();
    // ---- ph3: A mi4-7 kh1; stage t+2.B2,B3; counted gate for tile t+1 ----
#pragma unroll
    for (int m = 0; m < 4; ++m) a[m] = AF(cur, 4 + m, 4 + h);
    if (t + 2 < KTILES) { SB(cur, kk2, 2); SB(cur, kk2, 3); }
    SB0;
    if (t <= KTILES - 3) asm volatile("s_waitcnt vmcnt(6)" ::: "memory");
    else                 asm volatile("s_waitcnt vmcnt(0)" ::: "memory");
    __builtin_amdgcn_s_barrier();
    LGKM0;
    __builtin_amdgcn_s_setprio(1);
#pragma unroll
    for (int m = 0; m < 4; ++m)
#pragma unroll
      for (int n = 0; n < 4; ++n)
        acc[4 + m][n] = __builtin_amdgcn_mfma_f32_16x16x32_bf16(a[m], bk1[n], acc[4 + m][n], 0, 0, 0);
    __builtin_amdgcn_s_setprio(0);
    __builtin_amdgcn_s_barrier();
  }
#undef SA
#undef SB
#undef AF
#undef BF
#undef LGKM0
#undef SB0

  // epilogue: lams = softplus(hmu + lam1); loglik partial = obs*log(lams) - lams
  float lsum = 0.f;
  float* lams = out + 1;
#pragma unroll
  for (int mi = 0; mi < 8; ++mi) {
    int krow0 = kb * 256 + wm * 128 + mi * 16 + h * 4;
#pragma unroll
    for (int ni = 0; ni < 4; ++ni) {
      int t = tb * 256 + wn * 64 + ni * 16 + r15;
#pragma unroll
      for (int r = 0; r < 4; ++r) {
        int krow = krow0 + r;
        float x = hmu[krow] + acc[mi][ni][r];
        float lam = fmaxf(x, 0.f) + __logf(1.f + __expf(-fabsf(x)));
        lams[(size_t)krow * NDIM + t] = lam;
        float o = (float)obs8[(size_t)krow * NDIM + t];
        lsum += o * __logf(lam) - lam;
      }
    }
  }
  lsum += __shfl_down(lsum, 32);
  lsum += __shfl_down(lsum, 16);
  lsum += __shfl_down(lsum, 8);
  lsum += __shfl_down(lsum, 4);
  lsum += __shfl_down(lsum, 2);
  lsum += __shfl_down(lsum, 1);
  __shared__ float wsum[8];
  if (lane == 0) wsum[wid] = lsum;
  __syncthreads();
  if (tid == 0) {
    float s = 0.f;
#pragma unroll
    for (int w = 0; w < 8; ++w) s += wsum[w];
    atomicAdd(out, s);
  }
}

extern "C" void kernel_launch(void* const* d_in, const int* in_sizes, int n_in,
                              void* d_out, int out_size, void* d_ws, size_t ws_size,
                              hipStream_t stream) {
  const float* obs    = (const float*)d_in[0];
  const float* halpha = (const float*)d_in[1];
  const float* hbeta  = (const float*)d_in[2];
  float* out = (float*)d_out;

  char* ws = (char*)d_ws;
  bf16_t* S_all = (bf16_t*)ws;                                   // 32 MB, [NDIM][KDIM]
  float*  carry = (float*)(ws + (size_t)NDIM * KDIM * 2);        // 1 MB, [K][CHUNKS]
  float*  hmu   = carry + (size_t)KDIM * CHUNKS;                 // 4 KB
  bf16_t* Ab    = (bf16_t*)(hmu + KDIM);                         // 2 MB
  unsigned char* obs8 = (unsigned char*)(Ab + (size_t)KDIM * KDIM);  // 16.8 MB

  hipMemsetAsync(d_out, 0, sizeof(float), stream);               // loglik accumulator
  k_phase1<<<2048, 256, 0, stream>>>(obs, hbeta, carry, hmu, halpha, Ab, obs8);
  k_phase3<<<(KDIM / 64) * CHUNKS, 64, 0, stream>>>(obs8, hbeta, carry, S_all);
  k_gemm<<<4 * (NDIM / 256), 512, 0, stream>>>(Ab, S_all, hmu, obs8, out);
}